// Round 1
// baseline (95.605 us; speedup 1.0000x reference)
//
#include <hip/hip_runtime.h>
#include <math.h>
#include <stdint.h>

#define NF 256      // in_features
#define NT 256      // num_trees
#define ND 6        // depth
#define NB 2048     // batch
#define NCOL (NT * ND)   // 1536
#define NLEAF 64         // 2^depth

typedef __attribute__((ext_vector_type(8))) short bf16x8;         // MFMA A/B frag
typedef __attribute__((ext_vector_type(4))) float f32x4;          // MFMA C/D frag
typedef __attribute__((ext_vector_type(4))) unsigned short u16x4; // 8B chunk

__device__ inline unsigned short f2bf(float f) {   // round-to-nearest-even bf16
    unsigned u = __float_as_uint(f);
    u += 0x7fffu + ((u >> 16) & 1u);
    return (unsigned short)(u >> 16);
}
__device__ inline float bf2f(unsigned short h) {
    return __uint_as_float(((unsigned)h) << 16);
}

// 16B global -> LDS direct (dest = wave-uniform base + lane*16)
__device__ inline void gld16(const void* g, void* l) {
    __builtin_amdgcn_global_load_lds(
        (const __attribute__((address_space(1))) unsigned int*)(uintptr_t)g,
        (__attribute__((address_space(3))) unsigned int*)(uintptr_t)l,
        16, 0, 0);
}

// ---------------------------------------------------------------------------
// Kernel 1: sparsemax per (tree,depth) column (Michelot fixed-point), plus
// one-time prep: x fp32 -> split bf16 hi/lo, and scale = exp(-log_temp).
// ---------------------------------------------------------------------------
__global__ __launch_bounds__(256) void setup_kernel(
    const float* __restrict__ fsl,       // [NF, NCOL]
    const float* __restrict__ x,         // [NB, NF]
    const float* __restrict__ lt,        // [NT, ND]
    unsigned short* __restrict__ fs_hi,  // [NCOL, NF]
    unsigned short* __restrict__ fs_lo,  // [NCOL, NF]
    unsigned short* __restrict__ x_hi,   // [NB, NF]
    unsigned short* __restrict__ x_lo,   // [NB, NF]
    float* __restrict__ scl)             // [NT, ND]
{
    const int tid  = threadIdx.x;
    const int lane = tid & 63;
    const int col  = blockIdx.x * 4 + (tid >> 6);

    float xv[4];
    #pragma unroll
    for (int j = 0; j < 4; j++)
        xv[j] = fsl[(lane + 64 * j) * NCOL + col];

    // max over 256
    float mx = fmaxf(fmaxf(xv[0], xv[1]), fmaxf(xv[2], xv[3]));
    #pragma unroll
    for (int off = 32; off > 0; off >>= 1)
        mx = fmaxf(mx, __shfl_xor(mx, off));
    #pragma unroll
    for (int j = 0; j < 4; j++) xv[j] -= mx;

    // tau_0 = (sum - 1)/256
    float s = (xv[0] + xv[1]) + (xv[2] + xv[3]);
    #pragma unroll
    for (int off = 32; off > 0; off >>= 1)
        s += __shfl_xor(s, off);
    float tau = (s - 1.0f) / 256.0f;

    // Michelot: S <- {x > tau}; tau <- (sum_S - 1)/|S|; stop when |S| stable.
    int prev = 256;
    for (int it = 0; it < 64; it++) {
        float ss = 0.0f, cc = 0.0f;
        #pragma unroll
        for (int j = 0; j < 4; j++)
            if (xv[j] > tau) { ss += xv[j]; cc += 1.0f; }
        #pragma unroll
        for (int off = 32; off > 0; off >>= 1) {
            ss += __shfl_xor(ss, off);
            cc += __shfl_xor(cc, off);
        }
        const int c = (int)cc;
        if (c == prev) break;
        prev = c;
        tau = (ss - 1.0f) / cc;
    }

    #pragma unroll
    for (int j = 0; j < 4; j++) {
        const float v = fmaxf(xv[j] - tau, 0.0f);
        const unsigned short h = f2bf(v);
        fs_hi[col * NF + lane + 64 * j] = h;
        fs_lo[col * NF + lane + 64 * j] = f2bf(v - bf2f(h));
    }

    // ---- x fp32 -> split bf16 (one-time; removes 16x redundant VALU in K2) --
    const int gid = blockIdx.x * 256 + tid;          // 0..98303
    for (int e = gid; e < NB * NF / 4; e += (NCOL / 4) * 256) {
        const float4 v = ((const float4*)x)[e];
        const float vv[4] = {v.x, v.y, v.z, v.w};
        u16x4 h, l;
        #pragma unroll
        for (int j = 0; j < 4; j++) {
            h[j] = f2bf(vv[j]);
            l[j] = f2bf(vv[j] - bf2f(h[j]));
        }
        ((u16x4*)x_hi)[e] = h;
        ((u16x4*)x_lo)[e] = l;
    }

    // ---- scale = exp(-log_temperature) ----
    if (gid < NT * ND) scl[gid] = __expf(-lt[gid]);
}

// ---------------------------------------------------------------------------
// Kernel 2: fused split-bf16 MFMA GEMM + tree evaluation.
// global_load_lds staging (zero-VALU), linear LDS + source-side XOR chunk
// swizzle, double-buffered 2-phase K-loop, coalesced epilogue.
// ---------------------------------------------------------------------------
#define TM 64
#define TN 96
#define TK 32

struct MainBuf {                       // 20 KB, rows of 32 u16 (64 B), linear
    unsigned short Ah[TM * TK];
    unsigned short Al[TM * TK];
    unsigned short Bh[TN * TK];
    unsigned short Bl[TN * TK];
};

union SMem {
    MainBuf mb[2];                     // 40 KB double buffer
    struct {
        float fv[TM][TN + 1];          // 64 x 97
        float resp[16][NLEAF + 4];     // padded to 68 (272 B rows, 16B-aligned)
        float th[16 * ND];
        float sc[16 * ND];
    } ep;                              // ~29.9 KB
};

__global__ __launch_bounds__(256) void gemm_tree_kernel(
    const unsigned short* __restrict__ x_hi,   // [NB, NF]
    const unsigned short* __restrict__ x_lo,
    const unsigned short* __restrict__ fs_hi,  // [NCOL, NF]
    const unsigned short* __restrict__ fs_lo,
    const float* __restrict__ thr,             // [NT, ND]
    const float* __restrict__ scl,             // [NT, ND] = exp(-ltemp)
    const float* __restrict__ resp_g,          // [NT, 1, NLEAF]
    float* __restrict__ out)                   // [NB, NT]
{
    __shared__ SMem sm;

    const int tid  = threadIdx.x;
    const int lane = tid & 63;
    const int w    = tid >> 6;
    const int wm   = w & 1;
    const int wn   = w >> 1;
    const int bm0  = blockIdx.y * TM;
    const int bn0  = blockIdx.x * TN;
    const int t0   = blockIdx.x * 16;

    const int l15  = lane & 15;
    const int quad = lane >> 4;

    // staging decode: lane -> (row-within-16, dest chunk)
    const int lr = lane >> 2;     // 0..15
    const int cp = lane & 3;      // dest 16B chunk

    // A: wave w stages rows w*16..w*16+15 (hi & lo). Source chunk is the
    // inverse XOR swizzle so linear LDS == swizzled layout.
    const int rA  = (w << 4) + lr;
    const int cA  = cp ^ ((rA >> 1) & 3);
    const unsigned short* pAh = x_hi + (bm0 + rA) * NF + cA * 8;
    const unsigned short* pAl = x_lo + (bm0 + rA) * NF + cA * 8;

    // B: 6 segments of 16 rows; wave w does s=w, and s=w+4 when w<2.
    const int s0  = w;
    const int rB0 = (s0 << 4) + lr;
    const int cB0 = cp ^ ((rB0 >> 1) & 3);
    const unsigned short* pBh0 = fs_hi + (bn0 + rB0) * NF + cB0 * 8;
    const unsigned short* pBl0 = fs_lo + (bn0 + rB0) * NF + cB0 * 8;
    const int s1  = w + 4;
    const int rB1 = (s1 << 4) + lr;
    const int cB1 = cp ^ ((rB1 >> 1) & 3);
    const unsigned short* pBh1 = fs_hi + (bn0 + rB1) * NF + cB1 * 8;
    const unsigned short* pBl1 = fs_lo + (bn0 + rB1) * NF + cB1 * 8;

    auto stage = [&](int kb, int k0) {
        MainBuf& b = sm.mb[kb];
        gld16(pAh + k0, &b.Ah[w << 9]);
        gld16(pAl + k0, &b.Al[w << 9]);
        gld16(pBh0 + k0, &b.Bh[s0 << 9]);
        gld16(pBl0 + k0, &b.Bl[s0 << 9]);
        if (w < 2) {
            gld16(pBh1 + k0, &b.Bh[s1 << 9]);
            gld16(pBl1 + k0, &b.Bl[s1 << 9]);
        }
    };

    f32x4 acc[2][3] = {};

    stage(0, 0);
    __syncthreads();                 // drains vmcnt: buf0 ready

    #pragma unroll
    for (int t = 0; t < NF / TK; ++t) {      // 8 K-steps
        const int kb = t & 1;
        if (t < NF / TK - 1) stage(kb ^ 1, (t + 1) * TK);   // prefetch next

        MainBuf& b = sm.mb[kb];
        #pragma unroll
        for (int im = 0; im < 2; im++) {
            const int ar = wm * 32 + im * 16 + l15;
            const int sa = (quad ^ ((ar >> 1) & 3)) * 8;
            const bf16x8 a_h = *(const bf16x8*)&b.Ah[ar * TK + sa];
            const bf16x8 a_l = *(const bf16x8*)&b.Al[ar * TK + sa];
            #pragma unroll
            for (int in = 0; in < 3; in++) {
                const int br = wn * 48 + in * 16 + l15;
                const int sb = (quad ^ ((br >> 1) & 3)) * 8;
                const bf16x8 b_h = *(const bf16x8*)&b.Bh[br * TK + sb];
                const bf16x8 b_l = *(const bf16x8*)&b.Bl[br * TK + sb];
                acc[im][in] = __builtin_amdgcn_mfma_f32_16x16x32_bf16(a_h, b_h, acc[im][in], 0, 0, 0);
                acc[im][in] = __builtin_amdgcn_mfma_f32_16x16x32_bf16(a_h, b_l, acc[im][in], 0, 0, 0);
                acc[im][in] = __builtin_amdgcn_mfma_f32_16x16x32_bf16(a_l, b_h, acc[im][in], 0, 0, 0);
            }
        }
        __syncthreads();   // waves done with buf kb; prefetched buf drained
    }

    // ---- epilogue: fv -> LDS (C/D map: row=quad*4+r, col=l15) ----
    #pragma unroll
    for (int im = 0; im < 2; im++)
        #pragma unroll
        for (int in = 0; in < 3; in++)
            #pragma unroll
            for (int r = 0; r < 4; r++) {
                const int m = wm * 32 + im * 16 + quad * 4 + r;
                const int n = wn * 48 + in * 16 + l15;
                sm.ep.fv[m][n] = acc[im][in][r];
            }
    {
        const int tr  = tid >> 4;
        const int seg = (tid & 15) * 4;
        *(f32x4*)&sm.ep.resp[tr][seg] = *(const f32x4*)&resp_g[(t0 + tr) * NLEAF + seg];
    }
    if (tid < 16 * ND)       sm.ep.th[tid]      = thr[t0 * ND + tid];
    else if (tid < 32 * ND)  sm.ep.sc[tid - 96] = scl[t0 * ND + tid - 96];
    __syncthreads();

    // ---- tree evaluation: lane -> (m-row, tree); 16 consecutive trees per
    //      16 lanes => coalesced 64B output segments ----
    const int t16 = tid & 15;
    const int mr  = tid >> 4;     // 0..15
    #pragma unroll
    for (int i = 0; i < 4; i++) {
        const int m = mr + 16 * i;

        float sp[ND], sn[ND];
        #pragma unroll
        for (int d = 0; d < ND; d++) {
            const float f  = sm.ep.fv[m][t16 * ND + d];
            const float tl = (f - sm.ep.th[t16 * ND + d]) * sm.ep.sc[t16 * ND + d];
            const float h  = 0.5f * tl;
            sp[d] = fminf(fmaxf(0.5f + h, 0.0f), 1.0f);  // bit==0 factor
            sn[d] = fminf(fmaxf(0.5f - h, 0.0f), 1.0f);  // bit==1 factor
        }

        // fold-down contraction: out = sum_c resp[c] * prod_d s_d(bit_d(c))
        float r[32];
        #pragma unroll
        for (int c = 0; c < 32; c++)
            r[c] = sp[5] * sm.ep.resp[t16][c] + sn[5] * sm.ep.resp[t16][c + 32];
        #pragma unroll
        for (int d = 4; d >= 0; d--) {
            const int half = 1 << d;
            #pragma unroll
            for (int c = 0; c < 32; c++)
                if (c < half) r[c] = sp[d] * r[c] + sn[d] * r[c + half];
        }

        out[(bm0 + m) * NT + t0 + t16] = r[0];
    }
}

// ---------------------------------------------------------------------------
extern "C" void kernel_launch(void* const* d_in, const int* in_sizes, int n_in,
                              void* d_out, int out_size, void* d_ws, size_t ws_size,
                              hipStream_t stream)
{
    const float* x    = (const float*)d_in[0];  // [2048, 256]
    const float* resp = (const float*)d_in[1];  // [256, 1, 64]
    const float* fsl  = (const float*)d_in[2];  // [256, 256*6]
    const float* thr  = (const float*)d_in[3];  // [256, 6]
    const float* lt   = (const float*)d_in[4];  // [256, 6]
    float* out = (float*)d_out;                 // [2048, 256]

    unsigned short* fs_hi = (unsigned short*)d_ws;            // [NCOL, NF]
    unsigned short* fs_lo = fs_hi + (size_t)NCOL * NF;
    unsigned short* x_hi  = fs_lo + (size_t)NCOL * NF;        // [NB, NF]
    unsigned short* x_lo  = x_hi + (size_t)NB * NF;
    float*          scl   = (float*)(x_lo + (size_t)NB * NF); // [NT, ND]

    setup_kernel<<<NCOL / 4, 256, 0, stream>>>(fsl, x, lt, fs_hi, fs_lo, x_hi, x_lo, scl);

    dim3 g(NCOL / TN, NB / TM);   // (16, 32)
    gemm_tree_kernel<<<g, 256, 0, stream>>>(x_hi, x_lo, fs_hi, fs_lo, thr, scl, resp, out);
}